// Round 18
// baseline (269.581 us; speedup 1.0000x reference)
//
#include <hip/hip_runtime.h>
#include <math.h>

constexpr int NUM_CLASSES = 100;
constexpr int CACHE_SIZE  = 50;
constexpr int NPROT       = 5000;   // NUM_CLASSES*CACHE_SIZE
constexpr int FD          = 128;
constexpr int BATCH       = 2048;
constexpr int NROWS       = 4096;   // BATCH*NVIEWS
constexpr int TOPK        = 10;
constexpr float INV_TEMP  = 10.0f;  // 1/0.1
constexpr float PROTO_M   = 0.99f;
constexpr int PLD         = 5120;   // padded leading dim for partial buffers
constexpr int SROWS       = 16;     // rows per sink block (1024 thr, 256 blocks)
constexpr int NSLOT       = NROWS / SROWS;   // 256 colsum slots
constexpr int NTILE       = 40;     // pcon 128-tiles (5120)
constexpr int NTRI        = NTILE * (NTILE + 1) / 2;   // 820 upper-tri blocks
constexpr int GEMM_MB     = 16;     // GEMM row-blocks (256 rows each)

// NOTE: "big" stores t = exp(10*score) as f16 (NOT the score). All consumers
// are functions of t: exp(20o)=t^2, softplus(10o)=log(1+t), exp(softplus)=1+t.
// GEMMs use single-product bf16 MFMA (score err ~2e-3, final-scalar err ~1e-2).
// LESSON (rounds 10 & 16): NO cooperative/grid.sync kernels — each grid.sync
// costs ~25-30us in device-scope fences on MI355X. Separate launches win.

typedef __attribute__((ext_vector_type(8))) short bf16x8;
typedef __attribute__((ext_vector_type(4))) float f32x4;
typedef __attribute__((ext_vector_type(4))) _Float16 f16x4;
typedef __attribute__((ext_vector_type(8))) _Float16 f16x8;

// ---------- helpers ----------
__device__ __forceinline__ float blockReduceSum(float v) {
  __shared__ float tmp[8];
  const int lane = threadIdx.x & 63;
  const int wid  = threadIdx.x >> 6;
  #pragma unroll
  for (int o = 32; o > 0; o >>= 1) v += __shfl_down(v, o, 64);
  __syncthreads();
  if (lane == 0) tmp[wid] = v;
  __syncthreads();
  const int nw = (blockDim.x + 63) >> 6;
  float s = 0.f;
  for (int i = 0; i < nw; ++i) s += tmp[i];
  return s;
}

__device__ __forceinline__ short f2bf(float x) {   // RNE fp32 -> bf16 bits
  union { float f; unsigned u; } v; v.f = x;
  const unsigned r = v.u + 0x7fffu + ((v.u >> 16) & 1u);
  return (short)(r >> 16);
}

// ---------- fused: build feats/protos bf16 AND class prep ----------
__global__ __launch_bounds__(1024) void k_build_prep(
    const float* __restrict__ features, const float* __restrict__ protos,
    const int* __restrict__ targets,
    float* __restrict__ feats, short* __restrict__ fb, short* __restrict__ pb,
    int* __restrict__ classbase, int* __restrict__ rowlist) {
  constexpr int NF4 = NROWS * (FD / 4);    // 131072
  constexpr int NP4 = NPROT * FD / 4;      // 160000
  __shared__ int t[BATCH];
  __shared__ short chcnt[8][NUM_CLASSES];
  __shared__ int   chpre[8][NUM_CLASSES];
  __shared__ int   ctot[NUM_CLASSES];
  __shared__ int   base[NUM_CLASSES + 1];
  if (blockIdx.x < 285) {
    const int w = blockIdx.x * 1024 + threadIdx.x;
    if (w < NF4) {
      const int n  = w >> 5;
      const int d4 = (w & 31) << 2;
      const int b  = n & (BATCH - 1);
      const int v  = n >> 11;
      const float4 src = *reinterpret_cast<const float4*>(features + ((size_t)b * 2 + v) * FD + d4);
      *reinterpret_cast<float4*>(feats + (size_t)n * FD + d4) = src;
      short4 h;
      h.x = f2bf(src.x); h.y = f2bf(src.y); h.z = f2bf(src.z); h.w = f2bf(src.w);
      *reinterpret_cast<short4*>(fb + (size_t)n * FD + d4) = h;
    } else if (w - NF4 < NP4) {
      const int u = w - NF4;
      const float4 v = *reinterpret_cast<const float4*>(protos + (size_t)u * 4);
      short4 h;
      h.x = f2bf(v.x); h.y = f2bf(v.y); h.z = f2bf(v.z); h.w = f2bf(v.w);
      *reinterpret_cast<short4*>(pb + (size_t)u * 4) = h;
    }
    return;
  }
  // block 285: class counts + prefix + rank-based rowlist
  for (int i = threadIdx.x; i < BATCH; i += 1024) t[i] = targets[i];
  __syncthreads();
  if (threadIdx.x < 8 * NUM_CLASSES) {
    const int ch = threadIdx.x / NUM_CLASSES;
    const int c  = threadIdx.x % NUM_CLASSES;
    int m = 0;
    const int i0 = ch << 8;
    for (int i = i0; i < i0 + 256; ++i) m += (t[i] == c);
    chcnt[ch][c] = (short)m;
  }
  __syncthreads();
  if (threadIdx.x < NUM_CLASSES) {
    const int c = threadIdx.x;
    int s = 0;
    #pragma unroll
    for (int ch = 0; ch < 8; ++ch) { chpre[ch][c] = s; s += chcnt[ch][c]; }
    ctot[c] = s;
  }
  __syncthreads();
  if (threadIdx.x == 0) {
    int s = 0;
    for (int c = 0; c < NUM_CLASSES; ++c) { base[c] = s; s += 2 * ctot[c]; }
    base[NUM_CLASSES] = s;
  }
  __syncthreads();
  if (threadIdx.x <= NUM_CLASSES) classbase[threadIdx.x] = base[threadIdx.x];
  for (int b = threadIdx.x; b < BATCH; b += 1024) {
    const int c  = t[b];
    const int ch = b >> 8;
    int r = chpre[ch][c];
    for (int i = ch << 8; i < b; ++i) r += (t[i] == c);
    const int bs  = base[c];
    const int cnt = (base[c + 1] - bs) >> 1;
    rowlist[bs + r] = b;                 // v=0 rows first (ascending b)
    rowlist[bs + cnt + r] = BATCH + b;   // then v=1 rows
  }
}

// ================== LDS-staged bf16 MFMA GEMM (single product) ==================
// 256x128 tile, 512 threads (8 waves x 32 rows). Stores t=exp(10*score) as f16;
// colsum partial accumulates tf^2 (slot = blockIdx.y, 16 slots).
__global__ __launch_bounds__(512) void k_gemm_mfma(
    const short* __restrict__ A, const short* __restrict__ B,
    int Nb, _Float16* __restrict__ C, float* __restrict__ colpart) {
  __shared__ __align__(16) short Bs[128 * 64];   // 16 KB
  __shared__ float red[8][128];
  const int tid  = threadIdx.x;
  const int wid  = tid >> 6;           // 0..7
  const int lane = tid & 63;
  const int lr   = lane & 15;
  const int kg   = lane >> 4;
  const int m0   = blockIdx.y * 256 + wid * 32;
  const int n0   = blockIdx.x * 128;

  f32x4 acc[2][8];
  #pragma unroll
  for (int i = 0; i < 2; ++i)
    #pragma unroll
    for (int j = 0; j < 8; ++j) acc[i][j] = (f32x4){0.f, 0.f, 0.f, 0.f};

  bool cval[8];
  #pragma unroll
  for (int j = 0; j < 8; ++j) cval[j] = (n0 + j * 16 + lr < Nb);

  const int scol = tid >> 2;           // staged col 0..127 (4 threads/col)
  const int sk   = (tid & 3) * 16;     // k-offset in half (bf16)
  const int gcol = min(n0 + scol, Nb - 1);

  #pragma unroll
  for (int h = 0; h < 2; ++h) {
    const int k0 = h * 64;
    if (h) __syncthreads();            // finish compute on previous half
    #pragma unroll
    for (int u = 0; u < 2; ++u) {
      const int kk2 = sk + u * 8;      // 8 bf16 = 16B
      const bf16x8 vb = *reinterpret_cast<const bf16x8*>(B + (size_t)gcol * FD + k0 + kk2);
      const int byteoff = (scol * 128 + kk2 * 2) ^ ((scol & 7) << 4);
      *reinterpret_cast<bf16x8*>(reinterpret_cast<char*>(&Bs[0]) + byteoff) = vb;
    }
    __syncthreads();
    #pragma unroll
    for (int kk = 0; kk < 2; ++kk) {
      const int kb = k0 + kk * 32 + kg * 8;
      bf16x8 av[2], bv[8];
      #pragma unroll
      for (int i = 0; i < 2; ++i)
        av[i] = *reinterpret_cast<const bf16x8*>(A + (size_t)(m0 + i * 16 + lr) * FD + kb);
      #pragma unroll
      for (int j = 0; j < 8; ++j) {
        const int col = j * 16 + lr;
        const int bo = (col * 128 + (kk * 32 + kg * 8) * 2) ^ ((col & 7) << 4);
        bv[j] = *reinterpret_cast<const bf16x8*>(reinterpret_cast<const char*>(&Bs[0]) + bo);
      }
      #pragma unroll
      for (int i = 0; i < 2; ++i)
        #pragma unroll
        for (int j = 0; j < 8; ++j)
          acc[i][j] = __builtin_amdgcn_mfma_f32_16x16x32_bf16(av[i], bv[j], acc[i][j], 0, 0, 0);
    }
  }

  // epilogue: store t=exp(10*score) as f16 + fused column partials of tf^2
  float csum[8];
  #pragma unroll
  for (int j = 0; j < 8; ++j) csum[j] = 0.f;
  #pragma unroll
  for (int i = 0; i < 2; ++i) {
    const int rbase = m0 + i * 16 + kg * 4;
    #pragma unroll
    for (int j = 0; j < 8; ++j) {
      if (!cval[j]) continue;
      const int col = n0 + j * 16 + lr;
      #pragma unroll
      for (int q = 0; q < 4; ++q) {
        const float tval = __expf(acc[i][j][q] * INV_TEMP);   // e^(10 o)
        const _Float16 tf = (_Float16)tval;
        C[(size_t)(rbase + q) * NPROT + col] = tf;
        const float t32 = (float)tf;
        csum[j] = fmaf(t32, t32, csum[j]);
      }
    }
  }
  __syncthreads();
  #pragma unroll
  for (int j = 0; j < 8; ++j) {
    float v = csum[j];
    v += __shfl_xor(v, 16, 64);
    v += __shfl_xor(v, 32, 64);
    if (lane < 16) red[wid][j * 16 + lane] = v;
  }
  __syncthreads();
  if (tid < 128) {
    const int col = n0 + tid;
    if (col < Nb) {
      float t = 0.f;
      #pragma unroll
      for (int w = 0; w < 8; ++w) t += red[w][tid];
      colpart[(size_t)blockIdx.y * PLD + col] = t;
    }
  }
}

// ---------- fused Sinkhorn pass (+optional mle main-sum), t-domain ----------
// 256 blocks x 1024 threads (16 waves). Wave w handles row w.
template <bool WITH_MLE>
__global__ __launch_bounds__(1024) void k_sink_fused(const _Float16* __restrict__ big,
                                                     const float* __restrict__ Rin,
                                                     float* __restrict__ part,
                                                     float* __restrict__ semain,
                                                     const float* __restrict__ beta_ptr) {
  __shared__ float Cl[SROWS];
  const int r0   = blockIdx.x * SROWS;
  const int wid  = threadIdx.x >> 6;
  const int lane = threadIdx.x & 63;
  float beta = 0.f;
  bool bhalf = false;
  if constexpr (WITH_MLE) {
    beta = beta_ptr[0];
    bhalf = (beta == 0.5f);
  }
  // phase A: one wave per row (16 waves, 16 rows)
  {
    const int r = wid;
    const _Float16* row = big + (size_t)(r0 + r) * NPROT;
    float s = 0.f, se = 0.f;
    for (int idx = lane; idx < NPROT / 8; idx += 64) {
      const f16x8 v = *reinterpret_cast<const f16x8*>(row + idx * 8);
      const float4 q0 = *reinterpret_cast<const float4*>(Rin + idx * 8);
      const float4 q1 = *reinterpret_cast<const float4*>(Rin + idx * 8 + 4);
      float rt[8], rq[8];
      #pragma unroll
      for (int e = 0; e < 8; ++e) rt[e] = (float)v[e];
      rq[0] = q0.x; rq[1] = q0.y; rq[2] = q0.z; rq[3] = q0.w;
      rq[4] = q1.x; rq[5] = q1.y; rq[6] = q1.z; rq[7] = q1.w;
      #pragma unroll
      for (int e = 0; e < 8; ++e)
        s = fmaf(rt[e] * rt[e], rq[e], s);
      if constexpr (WITH_MLE) {
        #pragma unroll
        for (int e = 0; e < 8; ++e) {
          const float l = __logf(1.f + rt[e]);        // softplus(10o)
          const float lb = l + 1e-10f;
          const float imp = bhalf ? sqrtf(lb) : __expf(beta * __logf(lb));
          se += __expf(imp * l);
        }
      }
    }
    #pragma unroll
    for (int o = 32; o > 0; o >>= 1) {
      s += __shfl_down(s, o, 64);
      if constexpr (WITH_MLE) se += __shfl_down(se, o, 64);
    }
    if (lane == 0) {
      Cl[r] = 1.0f / s;
      if constexpr (WITH_MLE) semain[r0 + r] = se;
    }
  }
  __syncthreads();
  // phase B: column partials over this row strip (L2-resident re-read)
  for (int k4 = threadIdx.x * 4; k4 < NPROT; k4 += 4096) {
    float s[4] = {0.f, 0.f, 0.f, 0.f};
    #pragma unroll
    for (int r = 0; r < SROWS; ++r) {
      const f16x4 v = *reinterpret_cast<const f16x4*>(big + (size_t)(r0 + r) * NPROT + k4);
      const float c = Cl[r];
      #pragma unroll
      for (int e = 0; e < 4; ++e) {
        const float t = (float)v[e];
        s[e] = fmaf(t * t, c, s[e]);
      }
    }
    *reinterpret_cast<float4*>(part + (size_t)blockIdx.x * PLD + k4) =
        make_float4(s[0], s[1], s[2], s[3]);
  }
}

// ---------- parallel slot reduction: R[k] = 1/sum_slots part[slot][k] ----------
__global__ __launch_bounds__(512) void k_red_slots(const float* __restrict__ part,
                                                   int nslots, float* __restrict__ R) {
  __shared__ float red[8][64];
  const int g  = threadIdx.x >> 6;       // slot group 0..7
  const int kk = threadIdx.x & 63;
  const int k  = blockIdx.x * 64 + kk;
  float s = 0.f;
  if (k < NPROT) {
    const int per = nslots >> 3;
    const int b0 = g * per, b1 = b0 + per;
    for (int b = b0; b < b1; ++b) s += part[(size_t)b * PLD + k];
  }
  red[g][kk] = s;
  __syncthreads();
  if (threadIdx.x < 64 && k < NPROT) {
    float t = 0.f;
    #pragma unroll
    for (int g2 = 0; g2 < 8; ++g2) t += red[g2][kk];
    R[k] = 1.0f / t;
  }
}

// ---------- top-10 per row: one WAVE per row (weights = t^2*R3) ----------
__global__ __launch_bounds__(256) void k_top10(const _Float16* __restrict__ out1,
                                               const float* __restrict__ R3,
                                               const int* __restrict__ targets,
                                               float* __restrict__ wsel) {
  const int n = blockIdx.x * 4 + (threadIdx.x >> 6);
  const int lane = threadIdx.x & 63;
  const int c = targets[n & (BATCH - 1)];
  float cur = -1.0f, orig = -1.0f;
  if (lane < CACHE_SIZE) {
    const int k = c + lane * NUM_CLASSES;
    const float t = (float)out1[(size_t)n * NPROT + k];
    cur = t * t * R3[k];
    orig = cur;
  }
  float tvsum = 0.f;
  bool selme = false;
  #pragma unroll
  for (int i = 0; i < TOPK; ++i) {
    float bv = cur;
    int   bj = lane;
    #pragma unroll
    for (int o = 32; o > 0; o >>= 1) {
      const float ov = __shfl_xor(bv, o, 64);
      const int   oj = __shfl_xor(bj, o, 64);
      if (ov > bv || (ov == bv && oj < bj)) { bv = ov; bj = oj; }
    }
    tvsum += bv;
    if (lane == bj) { cur = -2.0f; selme = true; }
  }
  tvsum = fmaxf(tvsum, 1e-12f);
  if (lane < CACHE_SIZE)
    wsel[(size_t)n * CACHE_SIZE + lane] = selme ? orig / tvsum : 0.f;
}

// ---------- fused update_features + proto update/normalize/sim ----------
__global__ __launch_bounds__(128) void k_ufpu(const float* __restrict__ feats,
                                              const float* __restrict__ wsel,
                                              const int* __restrict__ rowlist,
                                              const int* __restrict__ classbase,
                                              const float* __restrict__ protos,
                                              short* __restrict__ pnb,
                                              float* __restrict__ simbuf) {
  const int k = blockIdx.x;
  const int d = threadIdx.x;
  const int c = k % NUM_CLASSES;
  const int j = k / NUM_CLASSES;
  const int b0 = classbase[c], b1 = classbase[c + 1];
  float u = 0.f;
  for (int ii = b0; ii < b1; ++ii) {
    const int n = rowlist[ii];
    const float wv = wsel[(size_t)n * CACHE_SIZE + j];
    if (wv != 0.f) u = fmaf(wv, feats[(size_t)n * FD + d], u);
  }
  const float p = protos[(size_t)k * FD + d];
  const float pnew = PROTO_M * p + (1.0f - PROTO_M) * u;
  const float spp = blockReduceSum(p * p);
  const float suu = blockReduceSum(u * u);
  const float sup = blockReduceSum(u * p);
  const float snn = blockReduceSum(pnew * pnew);
  const float x = pnew / fmaxf(sqrtf(snn), 1e-12f);
  pnb[(size_t)k * FD + d] = f2bf(x);
  if (d == 0)
    simbuf[k] = sup / (fmaxf(sqrtf(suu), 1e-12f) * fmaxf(sqrtf(spp), 1e-12f));
}

__global__ void k_tau(const float* __restrict__ simbuf, float* __restrict__ scalars) {
  float s = 0.f;
  for (int k = threadIdx.x; k < NPROT; k += 256) s += simbuf[k];
  s = blockReduceSum(s);
  if (threadIdx.x == 0) {
    const float sim_mean = s / (float)NPROT;
    scalars[0] = (1.0f + (0.5f - sim_mean)) * 0.4f;   // tau
  }
}

// ---------- mle finish: wave per row over the 50 in-class columns (t-domain) ----------
__global__ __launch_bounds__(256) void k_mle_fin(const _Float16* __restrict__ out2,
                                                 const float* __restrict__ R3,
                                                 const int* __restrict__ targets,
                                                 const float* __restrict__ wsel,
                                                 const float* __restrict__ beta_ptr,
                                                 const float* __restrict__ semain,
                                                 float* __restrict__ rowres) {
  const int n = blockIdx.x * 4 + (threadIdx.x >> 6);
  const int lane = threadIdx.x & 63;
  const int c = targets[n & (BATCH - 1)];
  const float beta = beta_ptr[0];
  const bool bhalf = (beta == 0.5f);
  float corr = 0.f, swl = 0.f, sw = 0.f;
  if (lane < CACHE_SIZE) {
    const int k = c + lane * NUM_CLASSES;
    const float t = (float)out2[(size_t)n * NPROT + k];
    const float l = __logf(1.f + t);          // softplus
    const float lb = l + 1e-10f;
    const float imp = bhalf ? sqrtf(lb) : __expf(beta * __logf(lb));
    corr = (1.f + t) - __expf(imp * l);       // exp(l)=1+t exactly
    if (wsel[(size_t)n * CACHE_SIZE + lane] > 0.f) {
      const float w2 = t * t * R3[k];         // exp(20o)*R3
      swl = w2 * l;
      sw  = w2;
    }
  }
  #pragma unroll
  for (int o = 32; o > 0; o >>= 1) {
    corr += __shfl_down(corr, o, 64);
    swl  += __shfl_down(swl,  o, 64);
    sw   += __shfl_down(sw,   o, 64);
  }
  if (lane == 0)
    rowres[n] = __logf(semain[n] + corr) - swl / fmaxf(sw, 1e-12f);
}

// ---------- proto contrast: symmetric upper-triangle MFMA (single product) ----------
__global__ __launch_bounds__(256) void k_pcon_mfma(
    const short* __restrict__ P, const float* __restrict__ scalars,
    float* __restrict__ part_neg, float* __restrict__ part_pos) {
  __shared__ __align__(16) short Bs[128 * 64];   // 16 KB; reused for col-side reduce
  int tdec = blockIdx.x, by = 0;
  while (tdec >= NTILE - by) { tdec -= NTILE - by; ++by; }
  const int bx = by + tdec;
  const bool diag = (bx == by);

  const int tid  = threadIdx.x;
  const int wid  = tid >> 6;
  const int lane = tid & 63;
  const int lr   = lane & 15;
  const int kg   = lane >> 4;
  const int k0r  = by * 128 + wid * 32;   // rows (protos "k")
  const int l0   = bx * 128;              // cols (protos "l")
  const float invtau = 1.0f / scalars[0];

  f32x4 acc[2][8];
  #pragma unroll
  for (int i = 0; i < 2; ++i)
    #pragma unroll
    for (int j = 0; j < 8; ++j) acc[i][j] = (f32x4){0.f, 0.f, 0.f, 0.f};

  int rowa[2];
  #pragma unroll
  for (int i = 0; i < 2; ++i) {
    const int r = k0r + i * 16 + lr;
    rowa[i] = (r < NPROT) ? r : (NPROT - 1);
  }
  bool cval[8];
  #pragma unroll
  for (int j = 0; j < 8; ++j) cval[j] = (l0 + j * 16 + lr < NPROT);

  const int scol = tid >> 1;
  const int sk   = (tid & 1) * 32;
  const int gcol = min(l0 + scol, NPROT - 1);

  #pragma unroll
  for (int h = 0; h < 2; ++h) {
    const int k0 = h * 64;
    if (h) __syncthreads();
    #pragma unroll
    for (int u = 0; u < 4; ++u) {
      const int kk2 = sk + u * 8;
      const bf16x8 vb = *reinterpret_cast<const bf16x8*>(P + (size_t)gcol * FD + k0 + kk2);
      const int byteoff = (scol * 128 + kk2 * 2) ^ ((scol & 7) << 4);
      *reinterpret_cast<bf16x8*>(reinterpret_cast<char*>(&Bs[0]) + byteoff) = vb;
    }
    __syncthreads();
    #pragma unroll
    for (int kk = 0; kk < 2; ++kk) {
      const int kb = k0 + kk * 32 + kg * 8;
      bf16x8 av[2], bv[8];
      #pragma unroll
      for (int i = 0; i < 2; ++i)
        av[i] = *reinterpret_cast<const bf16x8*>(P + (size_t)rowa[i] * FD + kb);
      #pragma unroll
      for (int j = 0; j < 8; ++j) {
        const int col = j * 16 + lr;
        const int bo = (col * 128 + (kk * 32 + kg * 8) * 2) ^ ((col & 7) << 4);
        bv[j] = *reinterpret_cast<const bf16x8*>(reinterpret_cast<const char*>(&Bs[0]) + bo);
      }
      #pragma unroll
      for (int i = 0; i < 2; ++i)
        #pragma unroll
        for (int j = 0; j < 8; ++j)
          acc[i][j] = __builtin_amdgcn_mfma_f32_16x16x32_bf16(av[i], bv[j], acc[i][j], 0, 0, 0);
    }
  }

  // epilogue: both-side accumulation in one pass over acc
  int ccls[8];
  #pragma unroll
  for (int j = 0; j < 8; ++j) ccls[j] = (l0 + j * 16 + lr) % NUM_CLASSES;
  float cneg[8], cpos[8];
  #pragma unroll
  for (int j = 0; j < 8; ++j) { cneg[j] = 0.f; cpos[j] = 0.f; }

  #pragma unroll
  for (int i = 0; i < 2; ++i) {
    float sneg[4] = {0.f, 0.f, 0.f, 0.f};
    float spos[4] = {0.f, 0.f, 0.f, 0.f};
    const int rbase = k0r + i * 16 + kg * 4;
    #pragma unroll
    for (int q = 0; q < 4; ++q) {
      const int rg = rbase + q;
      if (rg >= NPROT) continue;
      const int rcls = rg % NUM_CLASSES;
      #pragma unroll
      for (int j = 0; j < 8; ++j) {
        const int cg = l0 + j * 16 + lr;
        if (!cval[j]) continue;
        if (diag && cg == rg) continue;
        const float lg = fmaf(acc[i][j][q], invtau, -invtau);
        const float e  = __expf(lg);
        sneg[q] += e;
        cneg[j] += e;
        if (ccls[j] == rcls) { spos[q] += lg; cpos[j] += lg; }
      }
    }
    #pragma unroll
    for (int q = 0; q < 4; ++q) {
      float sn = sneg[q], sp = spos[q];
      #pragma unroll
      for (int off = 8; off > 0; off >>= 1) {
        sn += __shfl_xor(sn, off, 64);
        sp += __shfl_xor(sp, off, 64);
      }
      if (lr == 0) {
        const int rg = rbase + q;
        if (rg < NPROT) {
          part_neg[(size_t)bx * PLD + rg] = sn;
          part_pos[(size_t)bx * PLD + rg] = sp;
        }
      }
    }
  }

  if (!diag) {
    __syncthreads();   // all waves done with Bs (MFMA) -> reuse as reduce scratch
    float* redn = reinterpret_cast<float*>(&Bs[0]);     // [4][128]
    float* redp = redn + 512;                            // [4][128]
    #pragma unroll
    for (int j = 0; j < 8; ++j) {
      float cn = cneg[j];
      cn += __shfl_xor(cn, 16, 64);
      cn += __shfl_xor(cn, 32, 64);
      float cp = cpos[j];
      cp += __shfl_xor(cp, 16, 64);
      cp += __shfl_xor(cp, 32, 64);
      if (lane < 16) {
        redn[wid * 128 + j * 16 + lane] = cn;
        redp[wid * 128 + j * 16 + lane] = cp;
      }
    }
    __syncthreads();
    if (tid < 128) {
      const int cg = l0 + tid;
      if (cg < NPROT) {
        const float tn = redn[tid] + redn[128 + tid] + redn[256 + tid] + redn[384 + tid];
        const float tp = redp[tid] + redp[128 + tid] + redp[256 + tid] + redp[384 + tid];
        part_neg[(size_t)by * PLD + cg] = tn;
        part_pos[(size_t)by * PLD + cg] = tp;
      }
    }
  }
}

// ---------- pcon finish ----------
__global__ __launch_bounds__(256) void k_pcon_fin(const float* __restrict__ part_neg,
                                                  const float* __restrict__ part_pos,
                                                  float* __restrict__ pconbuf) {
  __shared__ float rn[4][64], rp[4][64];
  const int g  = threadIdx.x >> 6;
  const int kk = threadIdx.x & 63;
  const int k  = blockIdx.x * 64 + kk;
  float sn = 0.f, sp = 0.f;
  if (k < NPROT) {
    for (int b = g * 10; b < g * 10 + 10; ++b) {
      sn += part_neg[(size_t)b * PLD + k];
      sp += part_pos[(size_t)b * PLD + k];
    }
  }
  rn[g][kk] = sn; rp[g][kk] = sp;
  __syncthreads();
  if (threadIdx.x < 64 && k < NPROT) {
    const float tn = rn[0][kk] + rn[1][kk] + rn[2][kk] + rn[3][kk];
    const float tp = rp[0][kk] + rp[1][kk] + rp[2][kk] + rp[3][kk];
    pconbuf[k] = __logf(tn) - tp * (1.0f / (float)(CACHE_SIZE - 1));
  }
}

__global__ void k_final(const float* __restrict__ rowres,
                        const float* __restrict__ pconbuf,
                        float* __restrict__ outp) {
  float s1 = 0.f, s2 = 0.f;
  for (int i = threadIdx.x; i < NROWS; i += 256) s1 += rowres[i];
  for (int i = threadIdx.x; i < NPROT; i += 256) s2 += pconbuf[i];
  s1 = blockReduceSum(s1);
  s2 = blockReduceSum(s2);
  if (threadIdx.x == 0) outp[0] = s1 / (float)NROWS + s2 / (float)NPROT;
}

// ---------- host ----------
extern "C" void kernel_launch(void* const* d_in, const int* in_sizes, int n_in,
                              void* d_out, int out_size, void* d_ws, size_t ws_size,
                              hipStream_t stream) {
  (void)in_sizes; (void)n_in; (void)out_size; (void)ws_size;
  const float* features = (const float*)d_in[0];
  const int*   targets  = (const int*)d_in[1];
  const float* beta     = (const float*)d_in[2];
  const float* protos   = (const float*)d_in[3];
  float* outp = (float*)d_out;

  char* basep = (char*)d_ws;
  size_t off = 0;
  auto alloc = [&](size_t bytes) -> void* {
    void* p = basep + off;
    off = (off + bytes + 255) & ~(size_t)255;
    return p;
  };
  _Float16* big  = (_Float16*)alloc((size_t)NROWS * NPROT * 2);   // t-values, 40.96 MB
  float* feats   = (float*)alloc((size_t)NROWS * FD * 4);
  short* fb      = (short*)alloc((size_t)NROWS * FD * 2);
  short* pb      = (short*)alloc((size_t)NPROT * FD * 2);      // protos, then reused as pn
  float* part    = (float*)alloc((size_t)NSLOT * PLD * 4);     // 256 slots, 5.2 MB
  float* Rk      = (float*)alloc(NPROT * 4);
  float* wsel    = (float*)alloc((size_t)NROWS * CACHE_SIZE * 4);
  int*   rowlist = (int*)alloc(NROWS * 4);
  int*   classbase = (int*)alloc((NUM_CLASSES + 1) * 4);
  float* simbuf  = (float*)alloc(NPROT * 4);
  float* scalars = (float*)alloc(64);
  float* semain  = (float*)alloc(NROWS * 4);
  float* rowres  = (float*)alloc(NROWS * 4);
  float* pconbuf = (float*)alloc(NPROT * 4);
  float* pneg    = (float*)alloc((size_t)NTILE * PLD * 4);
  float* ppos    = (float*)alloc((size_t)NTILE * PLD * 4);

  k_build_prep<<<286, 1024, 0, stream>>>(features, protos, targets,
                                         feats, fb, pb, classbase, rowlist);

  // GEMM1 (fused colsum pass 1) + sinkhorn1
  k_gemm_mfma<<<dim3(40, GEMM_MB), 512, 0, stream>>>(fb, pb, NPROT, big, part);
  k_red_slots<<<79, 512, 0, stream>>>(part, GEMM_MB, Rk);                  // R1
  k_sink_fused<false><<<NSLOT, 1024, 0, stream>>>(big, Rk, part, nullptr, nullptr);
  k_red_slots<<<79, 512, 0, stream>>>(part, NSLOT, Rk);                    // R2
  k_sink_fused<false><<<NSLOT, 1024, 0, stream>>>(big, Rk, part, nullptr, nullptr);
  k_red_slots<<<79, 512, 0, stream>>>(part, NSLOT, Rk);                    // R3

  k_top10<<<NROWS / 4, 256, 0, stream>>>(big, Rk, targets, wsel);
  k_ufpu<<<NPROT, 128, 0, stream>>>(feats, wsel, rowlist, classbase, protos, pb, simbuf);
  k_tau<<<1, 256, 0, stream>>>(simbuf, scalars);

  // GEMM2 (fused colsum pass 1) + sinkhorn2 (pass2 carries mle main-sum)
  k_gemm_mfma<<<dim3(40, GEMM_MB), 512, 0, stream>>>(fb, pb, NPROT, big, part);
  k_red_slots<<<79, 512, 0, stream>>>(part, GEMM_MB, Rk);                  // R1'
  k_sink_fused<false><<<NSLOT, 1024, 0, stream>>>(big, Rk, part, nullptr, nullptr);
  k_red_slots<<<79, 512, 0, stream>>>(part, NSLOT, Rk);                    // R2'
  k_sink_fused<true><<<NSLOT, 1024, 0, stream>>>(big, Rk, part, semain, beta);
  k_red_slots<<<79, 512, 0, stream>>>(part, NSLOT, Rk);                    // R3'

  k_mle_fin<<<NROWS / 4, 256, 0, stream>>>(big, Rk, targets, wsel, beta, semain, rowres);
  k_pcon_mfma<<<NTRI, 256, 0, stream>>>(pb, scalars, pneg, ppos);
  k_pcon_fin<<<79, 256, 0, stream>>>(pneg, ppos, pconbuf);
  k_final<<<1, 256, 0, stream>>>(rowres, pconbuf, outp);
}

// Round 19
// 264.874 us; speedup vs baseline: 1.0178x; 1.0178x over previous
//
#include <hip/hip_runtime.h>
#include <math.h>

constexpr int NUM_CLASSES = 100;
constexpr int CACHE_SIZE  = 50;
constexpr int NPROT       = 5000;   // NUM_CLASSES*CACHE_SIZE
constexpr int FD          = 128;
constexpr int BATCH       = 2048;
constexpr int NROWS       = 4096;   // BATCH*NVIEWS
constexpr int TOPK        = 10;
constexpr float INV_TEMP  = 10.0f;  // 1/0.1
constexpr float PROTO_M   = 0.99f;
constexpr int PLD         = 5120;   // padded leading dim for partial buffers
constexpr int SROWS       = 16;     // rows per sink block (1024 thr, 256 blocks)
constexpr int NSLOT       = NROWS / SROWS;   // 256 colsum slots
constexpr int NTILE       = 40;     // pcon 128-tiles (5120)
constexpr int NTRI        = NTILE * (NTILE + 1) / 2;   // 820 upper-tri blocks
constexpr int CLD         = 64;     // compact in-class buffer leading dim

// NOTE: "big" stores t = exp(10*score) as f16 (NOT the score). All consumers
// are functions of t: exp(20o)=t^2, softplus(10o)=log(1+t), exp(softplus)=1+t.
// GEMMs use single-product bf16 MFMA (score err ~2e-3, final-scalar err ~1e-2).
// GEMM epilogue also scatters the 50 in-class t's per row into compact[n][j]
// (coalesced consumption by top10/mle_fin instead of stride-200B gathers).
// LESSON (rounds 10 & 16): NO cooperative/grid.sync kernels — each grid.sync
// costs ~25-30us in device-scope fences on MI355X. Separate launches win.

typedef __attribute__((ext_vector_type(8))) short bf16x8;
typedef __attribute__((ext_vector_type(4))) float f32x4;
typedef __attribute__((ext_vector_type(4))) _Float16 f16x4;
typedef __attribute__((ext_vector_type(8))) _Float16 f16x8;

// ---------- helpers ----------
__device__ __forceinline__ float blockReduceSum(float v) {
  __shared__ float tmp[8];
  const int lane = threadIdx.x & 63;
  const int wid  = threadIdx.x >> 6;
  #pragma unroll
  for (int o = 32; o > 0; o >>= 1) v += __shfl_down(v, o, 64);
  __syncthreads();
  if (lane == 0) tmp[wid] = v;
  __syncthreads();
  const int nw = (blockDim.x + 63) >> 6;
  float s = 0.f;
  for (int i = 0; i < nw; ++i) s += tmp[i];
  return s;
}

__device__ __forceinline__ short f2bf(float x) {   // RNE fp32 -> bf16 bits
  union { float f; unsigned u; } v; v.f = x;
  const unsigned r = v.u + 0x7fffu + ((v.u >> 16) & 1u);
  return (short)(r >> 16);
}

// ---------- fused: build feats/protos bf16 AND class prep ----------
__global__ __launch_bounds__(1024) void k_build_prep(
    const float* __restrict__ features, const float* __restrict__ protos,
    const int* __restrict__ targets,
    float* __restrict__ feats, short* __restrict__ fb, short* __restrict__ pb,
    int* __restrict__ classbase, int* __restrict__ rowlist) {
  constexpr int NF4 = NROWS * (FD / 4);    // 131072
  constexpr int NP4 = NPROT * FD / 4;      // 160000
  __shared__ int t[BATCH];
  __shared__ short chcnt[8][NUM_CLASSES];
  __shared__ int   chpre[8][NUM_CLASSES];
  __shared__ int   ctot[NUM_CLASSES];
  __shared__ int   base[NUM_CLASSES + 1];
  if (blockIdx.x < 285) {
    const int w = blockIdx.x * 1024 + threadIdx.x;
    if (w < NF4) {
      const int n  = w >> 5;
      const int d4 = (w & 31) << 2;
      const int b  = n & (BATCH - 1);
      const int v  = n >> 11;
      const float4 src = *reinterpret_cast<const float4*>(features + ((size_t)b * 2 + v) * FD + d4);
      *reinterpret_cast<float4*>(feats + (size_t)n * FD + d4) = src;
      short4 h;
      h.x = f2bf(src.x); h.y = f2bf(src.y); h.z = f2bf(src.z); h.w = f2bf(src.w);
      *reinterpret_cast<short4*>(fb + (size_t)n * FD + d4) = h;
    } else if (w - NF4 < NP4) {
      const int u = w - NF4;
      const float4 v = *reinterpret_cast<const float4*>(protos + (size_t)u * 4);
      short4 h;
      h.x = f2bf(v.x); h.y = f2bf(v.y); h.z = f2bf(v.z); h.w = f2bf(v.w);
      *reinterpret_cast<short4*>(pb + (size_t)u * 4) = h;
    }
    return;
  }
  // block 285: class counts + prefix + rank-based rowlist
  for (int i = threadIdx.x; i < BATCH; i += 1024) t[i] = targets[i];
  __syncthreads();
  if (threadIdx.x < 8 * NUM_CLASSES) {
    const int ch = threadIdx.x / NUM_CLASSES;
    const int c  = threadIdx.x % NUM_CLASSES;
    int m = 0;
    const int i0 = ch << 8;
    for (int i = i0; i < i0 + 256; ++i) m += (t[i] == c);
    chcnt[ch][c] = (short)m;
  }
  __syncthreads();
  if (threadIdx.x < NUM_CLASSES) {
    const int c = threadIdx.x;
    int s = 0;
    #pragma unroll
    for (int ch = 0; ch < 8; ++ch) { chpre[ch][c] = s; s += chcnt[ch][c]; }
    ctot[c] = s;
  }
  __syncthreads();
  if (threadIdx.x == 0) {
    int s = 0;
    for (int c = 0; c < NUM_CLASSES; ++c) { base[c] = s; s += 2 * ctot[c]; }
    base[NUM_CLASSES] = s;
  }
  __syncthreads();
  if (threadIdx.x <= NUM_CLASSES) classbase[threadIdx.x] = base[threadIdx.x];
  for (int b = threadIdx.x; b < BATCH; b += 1024) {
    const int c  = t[b];
    const int ch = b >> 8;
    int r = chpre[ch][c];
    for (int i = ch << 8; i < b; ++i) r += (t[i] == c);
    const int bs  = base[c];
    const int cnt = (base[c + 1] - bs) >> 1;
    rowlist[bs + r] = b;                 // v=0 rows first (ascending b)
    rowlist[bs + cnt + r] = BATCH + b;   // then v=1 rows
  }
}

// ================== LDS-staged bf16 MFMA GEMM (single product) ==================
// 128x128 tile, 256 threads. Stores t=exp(10*score) as f16; colsum partial
// accumulates tf^2 (slot = blockIdx.y, 32 slots); scatters in-class t's to compact.
__global__ __launch_bounds__(256) void k_gemm_mfma(
    const short* __restrict__ A, const short* __restrict__ B,
    const int* __restrict__ targets,
    int Nb, _Float16* __restrict__ C, float* __restrict__ colpart,
    _Float16* __restrict__ compact) {
  __shared__ __align__(16) short Bs[128 * 64];   // 16 KB
  __shared__ float red[4][128];
  const int tid  = threadIdx.x;
  const int wid  = tid >> 6;
  const int lane = tid & 63;
  const int lr   = lane & 15;
  const int kg   = lane >> 4;
  const int m0   = blockIdx.y * 128 + wid * 32;
  const int n0   = blockIdx.x * 128;

  f32x4 acc[2][8];
  #pragma unroll
  for (int i = 0; i < 2; ++i)
    #pragma unroll
    for (int j = 0; j < 8; ++j) acc[i][j] = (f32x4){0.f, 0.f, 0.f, 0.f};

  bool cval[8];
  #pragma unroll
  for (int j = 0; j < 8; ++j) cval[j] = (n0 + j * 16 + lr < Nb);

  const int scol = tid >> 1;           // staged col 0..127
  const int sk   = (tid & 1) * 32;     // k-offset in half (bf16)
  const int gcol = min(n0 + scol, Nb - 1);

  #pragma unroll
  for (int h = 0; h < 2; ++h) {
    const int k0 = h * 64;
    if (h) __syncthreads();            // finish compute on previous half
    #pragma unroll
    for (int u = 0; u < 4; ++u) {
      const int kk2 = sk + u * 8;      // 8 bf16 = 16B
      const bf16x8 vb = *reinterpret_cast<const bf16x8*>(B + (size_t)gcol * FD + k0 + kk2);
      const int byteoff = (scol * 128 + kk2 * 2) ^ ((scol & 7) << 4);
      *reinterpret_cast<bf16x8*>(reinterpret_cast<char*>(&Bs[0]) + byteoff) = vb;
    }
    __syncthreads();
    #pragma unroll
    for (int kk = 0; kk < 2; ++kk) {
      const int kb = k0 + kk * 32 + kg * 8;
      bf16x8 av[2], bv[8];
      #pragma unroll
      for (int i = 0; i < 2; ++i)
        av[i] = *reinterpret_cast<const bf16x8*>(A + (size_t)(m0 + i * 16 + lr) * FD + kb);
      #pragma unroll
      for (int j = 0; j < 8; ++j) {
        const int col = j * 16 + lr;
        const int bo = (col * 128 + (kk * 32 + kg * 8) * 2) ^ ((col & 7) << 4);
        bv[j] = *reinterpret_cast<const bf16x8*>(reinterpret_cast<const char*>(&Bs[0]) + bo);
      }
      #pragma unroll
      for (int i = 0; i < 2; ++i)
        #pragma unroll
        for (int j = 0; j < 8; ++j)
          acc[i][j] = __builtin_amdgcn_mfma_f32_16x16x32_bf16(av[i], bv[j], acc[i][j], 0, 0, 0);
    }
  }

  // class metadata for in-class scatter
  int ccls[8], cdiv[8];
  #pragma unroll
  for (int j = 0; j < 8; ++j) {
    const int col = n0 + j * 16 + lr;
    ccls[j] = col % NUM_CLASSES;
    cdiv[j] = col / NUM_CLASSES;
  }
  int rcls[2][4];
  #pragma unroll
  for (int i = 0; i < 2; ++i)
    #pragma unroll
    for (int q = 0; q < 4; ++q)
      rcls[i][q] = targets[(m0 + i * 16 + kg * 4 + q) & (BATCH - 1)];

  // epilogue: store t=exp(10*score) as f16 + fused column partials of tf^2
  float csum[8];
  #pragma unroll
  for (int j = 0; j < 8; ++j) csum[j] = 0.f;
  #pragma unroll
  for (int i = 0; i < 2; ++i) {
    const int rbase = m0 + i * 16 + kg * 4;
    #pragma unroll
    for (int j = 0; j < 8; ++j) {
      if (!cval[j]) continue;
      const int col = n0 + j * 16 + lr;
      #pragma unroll
      for (int q = 0; q < 4; ++q) {
        const float tval = __expf(acc[i][j][q] * INV_TEMP);   // e^(10 o)
        const _Float16 tf = (_Float16)tval;
        C[(size_t)(rbase + q) * NPROT + col] = tf;
        if (ccls[j] == rcls[i][q])
          compact[(size_t)(rbase + q) * CLD + cdiv[j]] = tf;
        const float t32 = (float)tf;
        csum[j] = fmaf(t32, t32, csum[j]);
      }
    }
  }
  __syncthreads();
  #pragma unroll
  for (int j = 0; j < 8; ++j) {
    float v = csum[j];
    v += __shfl_xor(v, 16, 64);
    v += __shfl_xor(v, 32, 64);
    if (lane < 16) red[wid][j * 16 + lane] = v;
  }
  __syncthreads();
  if (tid < 128) {
    const int col = n0 + tid;
    if (col < Nb) {
      const float t = red[0][tid] + red[1][tid] + red[2][tid] + red[3][tid];
      colpart[(size_t)blockIdx.y * PLD + col] = t;
    }
  }
}

// ---------- fused Sinkhorn pass (+optional mle main-sum), t-domain ----------
// 256 blocks x 1024 threads (16 waves). Wave w handles row w.
template <bool WITH_MLE>
__global__ __launch_bounds__(1024) void k_sink_fused(const _Float16* __restrict__ big,
                                                     const float* __restrict__ Rin,
                                                     float* __restrict__ part,
                                                     float* __restrict__ semain,
                                                     const float* __restrict__ beta_ptr) {
  __shared__ float Cl[SROWS];
  const int r0   = blockIdx.x * SROWS;
  const int wid  = threadIdx.x >> 6;
  const int lane = threadIdx.x & 63;
  float beta = 0.f;
  bool bhalf = false;
  if constexpr (WITH_MLE) {
    beta = beta_ptr[0];
    bhalf = (beta == 0.5f);
  }
  // phase A: one wave per row (16 waves, 16 rows)
  {
    const int r = wid;
    const _Float16* row = big + (size_t)(r0 + r) * NPROT;
    float s = 0.f, se = 0.f;
    for (int idx = lane; idx < NPROT / 8; idx += 64) {
      const f16x8 v = *reinterpret_cast<const f16x8*>(row + idx * 8);
      const float4 q0 = *reinterpret_cast<const float4*>(Rin + idx * 8);
      const float4 q1 = *reinterpret_cast<const float4*>(Rin + idx * 8 + 4);
      float rt[8], rq[8];
      #pragma unroll
      for (int e = 0; e < 8; ++e) rt[e] = (float)v[e];
      rq[0] = q0.x; rq[1] = q0.y; rq[2] = q0.z; rq[3] = q0.w;
      rq[4] = q1.x; rq[5] = q1.y; rq[6] = q1.z; rq[7] = q1.w;
      #pragma unroll
      for (int e = 0; e < 8; ++e)
        s = fmaf(rt[e] * rt[e], rq[e], s);
      if constexpr (WITH_MLE) {
        #pragma unroll
        for (int e = 0; e < 8; ++e) {
          const float l = __logf(1.f + rt[e]);        // softplus(10o)
          const float lb = l + 1e-10f;
          const float imp = bhalf ? sqrtf(lb) : __expf(beta * __logf(lb));
          se += __expf(imp * l);
        }
      }
    }
    #pragma unroll
    for (int o = 32; o > 0; o >>= 1) {
      s += __shfl_down(s, o, 64);
      if constexpr (WITH_MLE) se += __shfl_down(se, o, 64);
    }
    if (lane == 0) {
      Cl[r] = 1.0f / s;
      if constexpr (WITH_MLE) semain[r0 + r] = se;
    }
  }
  __syncthreads();
  // phase B: column partials over this row strip (L2-resident re-read)
  for (int k4 = threadIdx.x * 4; k4 < NPROT; k4 += 4096) {
    float s[4] = {0.f, 0.f, 0.f, 0.f};
    #pragma unroll
    for (int r = 0; r < SROWS; ++r) {
      const f16x4 v = *reinterpret_cast<const f16x4*>(big + (size_t)(r0 + r) * NPROT + k4);
      const float c = Cl[r];
      #pragma unroll
      for (int e = 0; e < 4; ++e) {
        const float t = (float)v[e];
        s[e] = fmaf(t * t, c, s[e]);
      }
    }
    *reinterpret_cast<float4*>(part + (size_t)blockIdx.x * PLD + k4) =
        make_float4(s[0], s[1], s[2], s[3]);
  }
}

// ---------- parallel slot reduction: R[k] = 1/sum_slots part[slot][k] ----------
__global__ __launch_bounds__(512) void k_red_slots(const float* __restrict__ part,
                                                   int nslots, float* __restrict__ R) {
  __shared__ float red[8][64];
  const int g  = threadIdx.x >> 6;       // slot group 0..7
  const int kk = threadIdx.x & 63;
  const int k  = blockIdx.x * 64 + kk;
  float s = 0.f;
  if (k < NPROT) {
    const int per = nslots >> 3;
    const int b0 = g * per, b1 = b0 + per;
    for (int b = b0; b < b1; ++b) s += part[(size_t)b * PLD + k];
  }
  red[g][kk] = s;
  __syncthreads();
  if (threadIdx.x < 64 && k < NPROT) {
    float t = 0.f;
    #pragma unroll
    for (int g2 = 0; g2 < 8; ++g2) t += red[g2][kk];
    R[k] = 1.0f / t;
  }
}

// ---------- top-10 per row: one WAVE per row; reads compact (coalesced) ----------
__global__ __launch_bounds__(256) void k_top10(const _Float16* __restrict__ compact,
                                               const float* __restrict__ R3,
                                               const int* __restrict__ targets,
                                               float* __restrict__ wsel) {
  const int n = blockIdx.x * 4 + (threadIdx.x >> 6);
  const int lane = threadIdx.x & 63;
  const int c = targets[n & (BATCH - 1)];
  float cur = -1.0f, orig = -1.0f;
  if (lane < CACHE_SIZE) {
    const float t = (float)compact[(size_t)n * CLD + lane];
    cur = t * t * R3[c + lane * NUM_CLASSES];
    orig = cur;
  }
  float tvsum = 0.f;
  bool selme = false;
  #pragma unroll
  for (int i = 0; i < TOPK; ++i) {
    float bv = cur;
    int   bj = lane;
    #pragma unroll
    for (int o = 32; o > 0; o >>= 1) {
      const float ov = __shfl_xor(bv, o, 64);
      const int   oj = __shfl_xor(bj, o, 64);
      if (ov > bv || (ov == bv && oj < bj)) { bv = ov; bj = oj; }
    }
    tvsum += bv;
    if (lane == bj) { cur = -2.0f; selme = true; }
  }
  tvsum = fmaxf(tvsum, 1e-12f);
  if (lane < CACHE_SIZE)
    wsel[(size_t)n * CACHE_SIZE + lane] = selme ? orig / tvsum : 0.f;
}

// ---------- fused update_features + proto update/normalize/sim ----------
__global__ __launch_bounds__(128) void k_ufpu(const float* __restrict__ feats,
                                              const float* __restrict__ wsel,
                                              const int* __restrict__ rowlist,
                                              const int* __restrict__ classbase,
                                              const float* __restrict__ protos,
                                              short* __restrict__ pnb,
                                              float* __restrict__ simbuf) {
  const int k = blockIdx.x;
  const int d = threadIdx.x;
  const int c = k % NUM_CLASSES;
  const int j = k / NUM_CLASSES;
  const int b0 = classbase[c], b1 = classbase[c + 1];
  float u = 0.f;
  for (int ii = b0; ii < b1; ++ii) {
    const int n = rowlist[ii];
    const float wv = wsel[(size_t)n * CACHE_SIZE + j];
    if (wv != 0.f) u = fmaf(wv, feats[(size_t)n * FD + d], u);
  }
  const float p = protos[(size_t)k * FD + d];
  const float pnew = PROTO_M * p + (1.0f - PROTO_M) * u;
  const float spp = blockReduceSum(p * p);
  const float suu = blockReduceSum(u * u);
  const float sup = blockReduceSum(u * p);
  const float snn = blockReduceSum(pnew * pnew);
  const float x = pnew / fmaxf(sqrtf(snn), 1e-12f);
  pnb[(size_t)k * FD + d] = f2bf(x);
  if (d == 0)
    simbuf[k] = sup / (fmaxf(sqrtf(suu), 1e-12f) * fmaxf(sqrtf(spp), 1e-12f));
}

// ---------- mle finish: wave per row over the 50 in-class columns (compact) ----------
__global__ __launch_bounds__(256) void k_mle_fin(const _Float16* __restrict__ compact,
                                                 const float* __restrict__ R3,
                                                 const int* __restrict__ targets,
                                                 const float* __restrict__ wsel,
                                                 const float* __restrict__ beta_ptr,
                                                 const float* __restrict__ semain,
                                                 float* __restrict__ rowres) {
  const int n = blockIdx.x * 4 + (threadIdx.x >> 6);
  const int lane = threadIdx.x & 63;
  const int c = targets[n & (BATCH - 1)];
  const float beta = beta_ptr[0];
  const bool bhalf = (beta == 0.5f);
  float corr = 0.f, swl = 0.f, sw = 0.f;
  if (lane < CACHE_SIZE) {
    const float t = (float)compact[(size_t)n * CLD + lane];
    const float l = __logf(1.f + t);          // softplus
    const float lb = l + 1e-10f;
    const float imp = bhalf ? sqrtf(lb) : __expf(beta * __logf(lb));
    corr = (1.f + t) - __expf(imp * l);       // exp(l)=1+t exactly
    if (wsel[(size_t)n * CACHE_SIZE + lane] > 0.f) {
      const float w2 = t * t * R3[c + lane * NUM_CLASSES];   // exp(20o)*R3
      swl = w2 * l;
      sw  = w2;
    }
  }
  #pragma unroll
  for (int o = 32; o > 0; o >>= 1) {
    corr += __shfl_down(corr, o, 64);
    swl  += __shfl_down(swl,  o, 64);
    sw   += __shfl_down(sw,   o, 64);
  }
  if (lane == 0)
    rowres[n] = __logf(semain[n] + corr) - swl / fmaxf(sw, 1e-12f);
}

// ---------- proto contrast: symmetric upper-triangle MFMA (tau inlined) ----------
__global__ __launch_bounds__(256) void k_pcon_mfma(
    const short* __restrict__ P, const float* __restrict__ simbuf,
    float* __restrict__ part_neg, float* __restrict__ part_pos) {
  __shared__ __align__(16) short Bs[128 * 64];   // 16 KB; reused for col-side reduce
  int tdec = blockIdx.x, by = 0;
  while (tdec >= NTILE - by) { tdec -= NTILE - by; ++by; }
  const int bx = by + tdec;
  const bool diag = (bx == by);

  const int tid  = threadIdx.x;
  const int wid  = tid >> 6;
  const int lane = tid & 63;
  const int lr   = lane & 15;
  const int kg   = lane >> 4;
  const int k0r  = by * 128 + wid * 32;   // rows (protos "k")
  const int l0   = bx * 128;              // cols (protos "l")

  // inline tau (deterministic per block: fixed order reduce of simbuf)
  float ssim = 0.f;
  for (int k = tid; k < NPROT; k += 256) ssim += simbuf[k];
  ssim = blockReduceSum(ssim);
  const float sim_mean = ssim / (float)NPROT;
  const float invtau = 1.0f / ((1.0f + (0.5f - sim_mean)) * 0.4f);

  f32x4 acc[2][8];
  #pragma unroll
  for (int i = 0; i < 2; ++i)
    #pragma unroll
    for (int j = 0; j < 8; ++j) acc[i][j] = (f32x4){0.f, 0.f, 0.f, 0.f};

  int rowa[2];
  #pragma unroll
  for (int i = 0; i < 2; ++i) {
    const int r = k0r + i * 16 + lr;
    rowa[i] = (r < NPROT) ? r : (NPROT - 1);
  }
  bool cval[8];
  #pragma unroll
  for (int j = 0; j < 8; ++j) cval[j] = (l0 + j * 16 + lr < NPROT);

  const int scol = tid >> 1;
  const int sk   = (tid & 1) * 32;
  const int gcol = min(l0 + scol, NPROT - 1);

  #pragma unroll
  for (int h = 0; h < 2; ++h) {
    const int k0 = h * 64;
    __syncthreads();
    #pragma unroll
    for (int u = 0; u < 4; ++u) {
      const int kk2 = sk + u * 8;
      const bf16x8 vb = *reinterpret_cast<const bf16x8*>(P + (size_t)gcol * FD + k0 + kk2);
      const int byteoff = (scol * 128 + kk2 * 2) ^ ((scol & 7) << 4);
      *reinterpret_cast<bf16x8*>(reinterpret_cast<char*>(&Bs[0]) + byteoff) = vb;
    }
    __syncthreads();
    #pragma unroll
    for (int kk = 0; kk < 2; ++kk) {
      const int kb = k0 + kk * 32 + kg * 8;
      bf16x8 av[2], bv[8];
      #pragma unroll
      for (int i = 0; i < 2; ++i)
        av[i] = *reinterpret_cast<const bf16x8*>(P + (size_t)rowa[i] * FD + kb);
      #pragma unroll
      for (int j = 0; j < 8; ++j) {
        const int col = j * 16 + lr;
        const int bo = (col * 128 + (kk * 32 + kg * 8) * 2) ^ ((col & 7) << 4);
        bv[j] = *reinterpret_cast<const bf16x8*>(reinterpret_cast<const char*>(&Bs[0]) + bo);
      }
      #pragma unroll
      for (int i = 0; i < 2; ++i)
        #pragma unroll
        for (int j = 0; j < 8; ++j)
          acc[i][j] = __builtin_amdgcn_mfma_f32_16x16x32_bf16(av[i], bv[j], acc[i][j], 0, 0, 0);
    }
  }

  // epilogue: both-side accumulation in one pass over acc
  int ccls[8];
  #pragma unroll
  for (int j = 0; j < 8; ++j) ccls[j] = (l0 + j * 16 + lr) % NUM_CLASSES;
  float cneg[8], cpos[8];
  #pragma unroll
  for (int j = 0; j < 8; ++j) { cneg[j] = 0.f; cpos[j] = 0.f; }

  #pragma unroll
  for (int i = 0; i < 2; ++i) {
    float sneg[4] = {0.f, 0.f, 0.f, 0.f};
    float spos[4] = {0.f, 0.f, 0.f, 0.f};
    const int rbase = k0r + i * 16 + kg * 4;
    #pragma unroll
    for (int q = 0; q < 4; ++q) {
      const int rg = rbase + q;
      if (rg >= NPROT) continue;
      const int rcls = rg % NUM_CLASSES;
      #pragma unroll
      for (int j = 0; j < 8; ++j) {
        const int cg = l0 + j * 16 + lr;
        if (!cval[j]) continue;
        if (diag && cg == rg) continue;
        const float lg = fmaf(acc[i][j][q], invtau, -invtau);
        const float e  = __expf(lg);
        sneg[q] += e;
        cneg[j] += e;
        if (ccls[j] == rcls) { spos[q] += lg; cpos[j] += lg; }
      }
    }
    #pragma unroll
    for (int q = 0; q < 4; ++q) {
      float sn = sneg[q], sp = spos[q];
      #pragma unroll
      for (int off = 8; off > 0; off >>= 1) {
        sn += __shfl_xor(sn, off, 64);
        sp += __shfl_xor(sp, off, 64);
      }
      if (lr == 0) {
        const int rg = rbase + q;
        if (rg < NPROT) {
          part_neg[(size_t)bx * PLD + rg] = sn;
          part_pos[(size_t)bx * PLD + rg] = sp;
        }
      }
    }
  }

  if (!diag) {
    __syncthreads();   // all waves done with Bs (MFMA) -> reuse as reduce scratch
    float* redn = reinterpret_cast<float*>(&Bs[0]);     // [4][128]
    float* redp = redn + 512;                            // [4][128]
    #pragma unroll
    for (int j = 0; j < 8; ++j) {
      float cn = cneg[j];
      cn += __shfl_xor(cn, 16, 64);
      cn += __shfl_xor(cn, 32, 64);
      float cp = cpos[j];
      cp += __shfl_xor(cp, 16, 64);
      cp += __shfl_xor(cp, 32, 64);
      if (lane < 16) {
        redn[wid * 128 + j * 16 + lane] = cn;
        redp[wid * 128 + j * 16 + lane] = cp;
      }
    }
    __syncthreads();
    if (tid < 128) {
      const int cg = l0 + tid;
      if (cg < NPROT) {
        const float tn = redn[tid] + redn[128 + tid] + redn[256 + tid] + redn[384 + tid];
        const float tp = redp[tid] + redp[128 + tid] + redp[256 + tid] + redp[384 + tid];
        part_neg[(size_t)by * PLD + cg] = tn;
        part_pos[(size_t)by * PLD + cg] = tp;
      }
    }
  }
}

// ---------- pcon finish ----------
__global__ __launch_bounds__(256) void k_pcon_fin(const float* __restrict__ part_neg,
                                                  const float* __restrict__ part_pos,
                                                  float* __restrict__ pconbuf) {
  __shared__ float rn[4][64], rp[4][64];
  const int g  = threadIdx.x >> 6;
  const int kk = threadIdx.x & 63;
  const int k  = blockIdx.x * 64 + kk;
  float sn = 0.f, sp = 0.f;
  if (k < NPROT) {
    for (int b = g * 10; b < g * 10 + 10; ++b) {
      sn += part_neg[(size_t)b * PLD + k];
      sp += part_pos[(size_t)b * PLD + k];
    }
  }
  rn[g][kk] = sn; rp[g][kk] = sp;
  __syncthreads();
  if (threadIdx.x < 64 && k < NPROT) {
    const float tn = rn[0][kk] + rn[1][kk] + rn[2][kk] + rn[3][kk];
    const float tp = rp[0][kk] + rp[1][kk] + rp[2][kk] + rp[3][kk];
    pconbuf[k] = __logf(tn) - tp * (1.0f / (float)(CACHE_SIZE - 1));
  }
}

__global__ void k_final(const float* __restrict__ rowres,
                        const float* __restrict__ pconbuf,
                        float* __restrict__ outp) {
  float s1 = 0.f, s2 = 0.f;
  for (int i = threadIdx.x; i < NROWS; i += 256) s1 += rowres[i];
  for (int i = threadIdx.x; i < NPROT; i += 256) s2 += pconbuf[i];
  s1 = blockReduceSum(s1);
  s2 = blockReduceSum(s2);
  if (threadIdx.x == 0) outp[0] = s1 / (float)NROWS + s2 / (float)NPROT;
}

// ---------- host ----------
extern "C" void kernel_launch(void* const* d_in, const int* in_sizes, int n_in,
                              void* d_out, int out_size, void* d_ws, size_t ws_size,
                              hipStream_t stream) {
  (void)in_sizes; (void)n_in; (void)out_size; (void)ws_size;
  const float* features = (const float*)d_in[0];
  const int*   targets  = (const int*)d_in[1];
  const float* beta     = (const float*)d_in[2];
  const float* protos   = (const float*)d_in[3];
  float* outp = (float*)d_out;

  char* basep = (char*)d_ws;
  size_t off = 0;
  auto alloc = [&](size_t bytes) -> void* {
    void* p = basep + off;
    off = (off + bytes + 255) & ~(size_t)255;
    return p;
  };
  _Float16* big  = (_Float16*)alloc((size_t)NROWS * NPROT * 2);   // t-values, 40.96 MB
  _Float16* compact = (_Float16*)alloc((size_t)NROWS * CLD * 2);  // in-class t's, 512 KB
  float* feats   = (float*)alloc((size_t)NROWS * FD * 4);
  short* fb      = (short*)alloc((size_t)NROWS * FD * 2);
  short* pb      = (short*)alloc((size_t)NPROT * FD * 2);      // protos, then reused as pn
  float* part    = (float*)alloc((size_t)NSLOT * PLD * 4);     // 256 slots, 5.2 MB
  float* Rk      = (float*)alloc(NPROT * 4);
  float* wsel    = (float*)alloc((size_t)NROWS * CACHE_SIZE * 4);
  int*   rowlist = (int*)alloc(NROWS * 4);
  int*   classbase = (int*)alloc((NUM_CLASSES + 1) * 4);
  float* simbuf  = (float*)alloc(NPROT * 4);
  float* semain  = (float*)alloc(NROWS * 4);
  float* rowres  = (float*)alloc(NROWS * 4);
  float* pconbuf = (float*)alloc(NPROT * 4);
  float* pneg    = (float*)alloc((size_t)NTILE * PLD * 4);
  float* ppos    = (float*)alloc((size_t)NTILE * PLD * 4);

  k_build_prep<<<286, 1024, 0, stream>>>(features, protos, targets,
                                         feats, fb, pb, classbase, rowlist);

  // GEMM1 (fused colsum pass 1 + compact scatter) + sinkhorn1
  k_gemm_mfma<<<dim3(40, 32), 256, 0, stream>>>(fb, pb, targets, NPROT, big, part, compact);
  k_red_slots<<<79, 512, 0, stream>>>(part, 32, Rk);                       // R1
  k_sink_fused<false><<<NSLOT, 1024, 0, stream>>>(big, Rk, part, nullptr, nullptr);
  k_red_slots<<<79, 512, 0, stream>>>(part, NSLOT, Rk);                    // R2
  k_sink_fused<false><<<NSLOT, 1024, 0, stream>>>(big, Rk, part, nullptr, nullptr);
  k_red_slots<<<79, 512, 0, stream>>>(part, NSLOT, Rk);                    // R3

  k_top10<<<NROWS / 4, 256, 0, stream>>>(compact, Rk, targets, wsel);
  k_ufpu<<<NPROT, 128, 0, stream>>>(feats, wsel, rowlist, classbase, protos, pb, simbuf);

  // GEMM2 (fused colsum pass 1 + compact scatter) + sinkhorn2 (pass2 carries mle)
  k_gemm_mfma<<<dim3(40, 32), 256, 0, stream>>>(fb, pb, targets, NPROT, big, part, compact);
  k_red_slots<<<79, 512, 0, stream>>>(part, 32, Rk);                       // R1'
  k_sink_fused<false><<<NSLOT, 1024, 0, stream>>>(big, Rk, part, nullptr, nullptr);
  k_red_slots<<<79, 512, 0, stream>>>(part, NSLOT, Rk);                    // R2'
  k_sink_fused<true><<<NSLOT, 1024, 0, stream>>>(big, Rk, part, semain, beta);
  k_red_slots<<<79, 512, 0, stream>>>(part, NSLOT, Rk);                    // R3'

  k_mle_fin<<<NROWS / 4, 256, 0, stream>>>(compact, Rk, targets, wsel, beta, semain, rowres);
  k_pcon_mfma<<<NTRI, 256, 0, stream>>>(pb, simbuf, pneg, ppos);
  k_pcon_fin<<<79, 256, 0, stream>>>(pneg, ppos, pconbuf);
  k_final<<<1, 256, 0, stream>>>(rowres, pconbuf, outp);
}